// Round 9
// baseline (225.326 us; speedup 1.0000x reference)
//
#include <hip/hip_runtime.h>
#include <math.h>

typedef unsigned short u16;
typedef __attribute__((ext_vector_type(8))) short short8;
typedef __attribute__((ext_vector_type(4))) float floatx4;

constexpr int BATCH = 16;
constexpr int NI = 1024;
constexpr int CE = 64;
constexpr int CI = 16;
constexpr long long NN2  = (long long)NI * NI;          // 1M
constexpr long long BCN  = (long long)BATCH * CE * NI;  // 1M
constexpr long long BNv  = (long long)BATCH * NI;       // 16K
constexpr long long BNN  = (long long)BATCH * NI * NI;  // 16M
constexpr long long S1 = (long long)CE * NI;            // 65536
constexpr long long S2 = 2 * S1;                        // 131072
constexpr int ZERON = (int)(2 * BNv + 80);              // zero-init region elements

__device__ __forceinline__ float lrelu01(float x) { return x > 0.f ? x : 0.01f * x; }

__device__ __forceinline__ u16 f2bf(float f) {
  unsigned u = __builtin_bit_cast(unsigned, f);
  return (u16)((u + 0x7fffu + ((u >> 16) & 1u)) >> 16);  // RNE
}
__device__ __forceinline__ float bf2f(u16 h) {
  unsigned u = ((unsigned)h) << 16;
  return __builtin_bit_cast(float, u);
}
// monotonic uint key for float atomicMax (zero-init safe: real-float keys > 0)
__device__ __forceinline__ unsigned fkey(float f) {
  unsigned u = __builtin_bit_cast(unsigned, f);
  return (u & 0x80000000u) ? ~u : (u | 0x80000000u);
}
__device__ __forceinline__ float funkey(unsigned k) {
  unsigned u = (k & 0x80000000u) ? (k & 0x7fffffffu) : ~k;
  return __builtin_bit_cast(float, u);
}

// async global->LDS, 16B per lane. LDS dest is wave-uniform base + lane*16;
// swizzle is achieved by pre-swizzling the per-lane GLOBAL source (m173 pattern).
__device__ __forceinline__ void gload16(const u16* g, u16* l) {
  __builtin_amdgcn_global_load_lds(
      (const __attribute__((address_space(1))) void*)g,
      (__attribute__((address_space(3))) void*)l, 16, 0, 0);
}

// mode-13 fence: B(ki+2) (2 gload groups) stays in flight across the barrier
__device__ __forceinline__ void fence13() {
  __builtin_amdgcn_sched_barrier(0);
  asm volatile("s_waitcnt vmcnt(2) lgkmcnt(0)" ::: "memory");
  __builtin_amdgcn_s_barrier();
  __builtin_amdgcn_sched_barrier(0);
}

// counted-vmcnt fence: wait until <= N vector-mem groups outstanding, then barrier.
// All waves stage in lockstep, so post-barrier every wave's older tiles landed.
template<int N>
__device__ __forceinline__ void fence_bar() {
  __builtin_amdgcn_sched_barrier(0);
  if constexpr (N == 0) asm volatile("s_waitcnt vmcnt(0)" ::: "memory");
  else if constexpr (N == 1) asm volatile("s_waitcnt vmcnt(1)" ::: "memory");
  else if constexpr (N == 2) asm volatile("s_waitcnt vmcnt(2)" ::: "memory");
  else if constexpr (N == 3) asm volatile("s_waitcnt vmcnt(3)" ::: "memory");
  else if constexpr (N == 4) asm volatile("s_waitcnt vmcnt(4)" ::: "memory");
  else if constexpr (N == 6) asm volatile("s_waitcnt vmcnt(6)" ::: "memory");
  else asm volatile("s_waitcnt vmcnt(0)" ::: "memory");
  __builtin_amdgcn_s_barrier();
  __builtin_amdgcn_sched_barrier(0);
}

// ================= MFMA TN GEMM: C[r][m] = sum_k A[r][k] * Bt[m][k] ==============
// A, Bt bf16 row-major K-contiguous. BK=64, XOR-swizzled 16B chunks in LDS.
// MODE: 3 flat grid: [0,4096) gram exp + rowsum (XCD-grouped by z) |
//          [4096,5120) FULL unscaled Abig = [l1u+0|L1L1u; l2u+b2|L2L2u] (no Zgl dep)|
//       5 BK=128 super-steps (8 MFMA/barrier), pure gload_lds dual-B, depth-3
//          counted vmcnt(6); A pre-divided by Z (adiv); z%8==xcd matches mode-3
//          bigW writes so B reads are L2-warm; rank-1 + LN stats epilogue |
//       13 A = attention-p on the fly, 3-deep B pipe w/ counted vmcnt |
//       14 hT direct: +rank-1 + per-column s1/s2 dots + s2max, XCD flat grid |
//       15 flat grid: [0,512) G12 GEMM | [512,1536) csv2 rows | [1536,2048) y-GEMM
template<int BM, int BN, int MODE>
__global__ __launch_bounds__(256) void mgemm(
    const u16* __restrict__ Ag, const u16* __restrict__ B1g, const u16* __restrict__ B2g,
    int K1, int K, int lda, int ldb, long long bsA, long long bsB1,
    float* __restrict__ Cf, u16* __restrict__ Cb, int ldc, long long bsC,
    const float* __restrict__ aux1, const float* __restrict__ aux2,
    const float* __restrict__ aux3, const float* __restrict__ aux4,
    float* __restrict__ Zout)
{
  constexpr int RM = BM / 2, RN = BN / 2, MI = RM / 16, NJ = RN / 16;
  constexpr bool PIPE3 = (MODE == 14 || MODE == 15);
  constexpr int NBB = PIPE3 ? 3 : (MODE == 13 ? 3 : 1);
  constexpr int NBA = PIPE3 ? 3 : (MODE == 13 ? 2 : 1);
  constexpr int NLA = (BM * 8) / 256;  // per-thread A gload chunks per 64-K-tile
  constexpr int NLB = (BN * 8) / 256;
  constexpr int L = (NLA + NLB);       // gload groups per PIPE3 stage
  constexpr int ASZ = (MODE == 5) ? 3 * BM * 128 : NBA * BM * 64;
  constexpr int BSZ = (MODE == 5) ? 3 * BN * 128 : NBB * BN * 64;
  __shared__ __align__(16) u16 As[ASZ];
  __shared__ __align__(16) u16 Bs[BSZ];
  __shared__ __align__(16) u16 xa[MODE == 13 ? 32 * 72 : 1];  // stage-2 A tile (padded)
  const int tid = threadIdx.x;
  int z, n0, r0, job15 = 0;
  bool job4 = false;
  long long cboff = 0;
  if constexpr (MODE == 15) {
    const int id = blockIdx.x;
    if (id >= 512 && id < 1536) {
      // csv2: cs2[m]=colsum g2; v2[m]=(cs1@g2)[m].  aux3=gdata2raw, aux2=d2, aux1=cs1
      const int m = id - 512;
      float s = 0.f, sv = 0.f;
      for (int n = tid; n < NI; n += 256) {
        float g = aux3[(long long)m * NI + n] * aux2[n];
        s += g;
        sv = fmaf(g, aux1[n], sv);
      }
      float* r1 = (float*)As;
      float* r2 = (float*)As + 256;
      r1[tid] = s; r2[tid] = sv; __syncthreads();
      for (int st = 128; st > 0; st >>= 1) {
        if (tid < st) { r1[tid] += r1[tid + st]; r2[tid] += r2[tid + st]; }
        __syncthreads();
      }
      if (tid == 0) {
        float dm = aux2[m];
        Cf[m] = dm * (r1[0] + dm);
        Zout[m] = dm * (r2[0] + dm * aux1[m]);
      }
      return;
    }
    if (id >= 1536) {                       // y-GEMM: y = attwT @ h0a
      const int id2 = id - 1536;
      job15 = 2;
      z = id2 >> 5; r0 = (id2 & 1) * BM; n0 = ((id2 >> 1) & 15) * BN;
    } else {
      z = 0; n0 = (id & 15) * BN; r0 = (id >> 4) * BM;
    }
  } else if constexpr (MODE == 5) {
    // 1024 blocks. z%8 == xcd matches mode-3's bigW placement -> bigW_z (2 MB,
    // 2 z per XCD = 4 MB) is still resident in that XCD's L2 when we read it.
    const int fid = blockIdx.x;
    const int xcd = fid & 7, idx = fid >> 3;           // idx 0..127
    const int idx2 = idx >> 5;                         // 0..3
    z = xcd + (idx2 >> 1) * 8;
    r0 = (idx2 & 1) * BM;
    n0 = (idx & 31) * BN;
  } else if constexpr (MODE == 3) {
    const int id = blockIdx.x;
    if (id < 4096) {
      const int xcd = id & 7, idx = id >> 3;
      z = (idx >> 8) * 8 + xcd;              // 2 z's per XCD
      const int g = idx & 255;
      n0 = (g & 15) * 64; r0 = ((g >> 4) & 15) * 64;
    } else {                                 // full unscaled Abig (1024 blocks)
      const int t4 = id - 4096;              // 0..1023
      job4 = true;
      z = t4 >> 6;
      const int g = t4 & 63;
      r0 = (g >> 4) * 64;                    // yblk 0..3 -> stack4 rows
      n0 = (g & 15) * 64;
    }
  } else if constexpr (MODE == 13 || MODE == 14) {
    const int id = blockIdx.x;               // 512 blocks flat
    const int xcd = id & 7, idx = id >> 3;
    z = (idx >> 5) * 8 + xcd;                // 2 z's per XCD
    if constexpr (MODE == 13) { r0 = (idx & 31) * BM; n0 = 0; }
    else { n0 = (idx & 31) * BN; r0 = 0; }
  } else {
    z = blockIdx.z; n0 = blockIdx.x * BN; r0 = blockIdx.y * BM;
  }
  int Kv = K, K1v = K1, ldav = lda, ldbv = ldb;
  const u16 *Ab, *Bb1;
  if constexpr (MODE == 15) {
    if (job15 == 2) {
      Kv = 64; K1v = 128; ldav = 64; ldbv = 64;
      Ab = B2g + (long long)r0 * 64;                               // attwT_bf
      Bb1 = (const u16*)aux4 + (long long)z * S1 + (long long)n0 * 64;  // h0aT
      cboff = bsB1 + (long long)z * S1;                            // -> ybf
    } else {
      Ab = Ag + (long long)r0 * lda;
      Bb1 = B1g + (long long)n0 * ldb;
    }
  } else {
    Ab = Ag + (long long)z * bsA + (long long)r0 * ldav;
    Bb1 = B1g + (long long)z * bsB1 + (long long)n0 * ldbv;
    if constexpr (MODE == 3) {
      if (job4) Ab = ((const u16*)aux2) + (long long)r0 * 64;      // stack4 rows
    }
  }
  const int lane = tid & 63;
  const int wid = tid >> 6;
  const int wr = wid >> 1, wc = wid & 1;
  const int q = lane >> 4, mlow = lane & 15;
  const int wbase = tid & ~63;  // wave-uniform

  floatx4 acc[MI][NJ] = {};
  float zp0 = 0.f;  // MODE13 row p-sum (BM=32 -> single chunk/thread)

  // MODE13 per-thread row constants (k0-independent)
  float s1r_13 = 0.f, mr_13 = 0.f;
  const float* s2z_13 = nullptr;
  float4 sa, sb;  // MODE13 prefetched s2 values
  if constexpr (MODE == 13) {
    const float* s1z = aux2 + (long long)z * NI;
    s2z_13 = aux3 + (long long)z * NI;
    const float mb = funkey(((const unsigned*)aux4)[z]);
    s1r_13 = s1z[r0 + (tid >> 3)];
    mr_13 = lrelu01(s1r_13 + mb);
  }

  // ---- staging: global -> LDS (async), source pre-swizzled, LDS linear ----
  auto stageAB = [&](int buf, int k0) {
    if constexpr (MODE != 13) {
      const u16* Asrc = Ab + k0;
#pragma unroll
      for (int s = 0; s < NLA; s++) {
        int cid = tid + s * 256;
        int r = cid >> 3, cc = cid & 7;
        gload16(Asrc + (long long)r * ldav + ((cc ^ (r & 7)) << 3),
                As + buf * (BM * 64) + ((wbase + s * 256) << 3));
      }
    }
    const u16* Bsrc = (k0 < K1v) ? (Bb1 + k0)
                                 : (B2g + (long long)n0 * ldbv + (k0 - K1v));
#pragma unroll
    for (int s = 0; s < NLB; s++) {
      int cid = tid + s * 256;
      int r = cid >> 3, cc = cid & 7;
      gload16(Bsrc + (long long)r * ldbv + ((cc ^ (r & 7)) << 3),
              Bs + buf * (BN * 64) + ((wbase + s * 256) << 3));
    }
  };

  // ---- MODE13 A-tile gen, split: issue s2 loads FIRST (older than B gloads,
  // so the compiler's wait for sa/sb retires older B tiles but leaves the
  // just-issued B prefetch in flight) ----
  auto agen_ld = [&](int k0) {
    const float* sp = s2z_13 + k0 + (tid & 7) * 8;
    sa = *(const float4*)sp;
    sb = *(const float4*)(sp + 4);
  };
  auto agen_st = [&](int buf) {
    int r = tid >> 3, craw = tid & 7;
    float p0 = __expf(lrelu01(s1r_13 + sa.x) - mr_13);
    float p1 = __expf(lrelu01(s1r_13 + sa.y) - mr_13);
    float p2 = __expf(lrelu01(s1r_13 + sa.z) - mr_13);
    float p3 = __expf(lrelu01(s1r_13 + sa.w) - mr_13);
    float p4 = __expf(lrelu01(s1r_13 + sb.x) - mr_13);
    float p5 = __expf(lrelu01(s1r_13 + sb.y) - mr_13);
    float p6 = __expf(lrelu01(s1r_13 + sb.z) - mr_13);
    float p7 = __expf(lrelu01(s1r_13 + sb.w) - mr_13);
    zp0 += p0 + p1 + p2 + p3 + p4 + p5 + p6 + p7;
    uint4 v;
    v.x = (unsigned)f2bf(p0) | ((unsigned)f2bf(p1) << 16);
    v.y = (unsigned)f2bf(p2) | ((unsigned)f2bf(p3) << 16);
    v.z = (unsigned)f2bf(p4) | ((unsigned)f2bf(p5) << 16);
    v.w = (unsigned)f2bf(p6) | ((unsigned)f2bf(p7) << 16);
    *(uint4*)&As[buf * (BM * 64) + (r * 8 + (craw ^ (r & 7))) * 8] = v;
  };

  auto compute_tile = [&](int bufA, int bufB) {
#pragma unroll
    for (int kh = 0; kh < 2; kh++) {
      const int kc = kh * 4 + q;
      short8 afr[MI], bfr[NJ];
#pragma unroll
      for (int i = 0; i < MI; i++) {
        int row = wr * RM + i * 16 + mlow;
        afr[i] = *(const short8*)&As[bufA * (BM * 64) + (row * 8 + (kc ^ (row & 7))) * 8];
      }
#pragma unroll
      for (int j = 0; j < NJ; j++) {
        int row = wc * RN + j * 16 + mlow;
        bfr[j] = *(const short8*)&Bs[bufB * (BN * 64) + (row * 8 + (kc ^ (row & 7))) * 8];
      }
#pragma unroll
      for (int i = 0; i < MI; i++)
#pragma unroll
        for (int j = 0; j < NJ; j++)
          acc[i][j] = __builtin_amdgcn_mfma_f32_16x16x32_bf16(afr[i], bfr[j], acc[i][j], 0, 0, 0);
    }
  };

  if constexpr (PIPE3) {
    // 3-deep pipeline, counted vmcnt: tiles ki+1..ki+2 stay in flight.
    const int nk = Kv >> 6;
#pragma unroll
    for (int p = 0; p < 2; p++) {
      int kk = (p < nk) ? p : (nk - 1);   // clamp for short-K jobs (no OOB)
      stageAB(p, kk << 6);
    }
    fence_bar<L>();  // retire tile 0 everywhere
    int cur = 0, stg = 2;
    for (int ki = 0; ki < nk; ki++) {
      if (ki + 2 < nk) stageAB(stg, (ki + 2) << 6);
      compute_tile(cur, cur);
      if (ki + 1 < nk) {
        const int rem = nk - 1 - ki;
        const int u = (rem < 2) ? rem : 2;
        if (u == 2) fence_bar<L>();
        else fence_bar<0>();
      }
      cur++; if (cur == NBB) cur = 0;
      stg++; if (stg == NBB) stg = 0;
    }
    __syncthreads();  // drain + protect LDS reuse in epilogues
  } else if constexpr (MODE == 5) {
    // BK=128 super-steps: 8 MFMA + 12 ds_read per barrier (2x amortization of
    // the ~300-cyc fence+barrier overhead that bound the BK=64 variants at
    // ~195 TF). Pure gload_lds staging (A pre-divided by adiv); depth-3
    // counted pipeline: 6 groups per stage, vmcnt(6) steady-state.
    const int ns = Kv >> 7;  // 16
    auto stage5 = [&](int buf, int s) {
#pragma unroll
      for (int sub = 0; sub < 2; sub++) {
        const int k0 = (s << 7) + (sub << 6);
        const u16* Asrc = Ab + k0;
#pragma unroll
        for (int g = 0; g < NLA; g++) {
          int cid = tid + g * 256;
          int r = cid >> 3, cc = cid & 7;
          gload16(Asrc + (long long)r * ldav + ((cc ^ (r & 7)) << 3),
                  As + buf * (BM * 128) + sub * (BM * 64) + ((wbase + g * 256) << 3));
        }
        const u16* Bsrc = (k0 < K1v) ? (Bb1 + k0)
                                     : (B2g + (long long)n0 * ldbv + (k0 - K1v));
#pragma unroll
        for (int g = 0; g < NLB; g++) {
          int cid = tid + g * 256;
          int r = cid >> 3, cc = cid & 7;
          gload16(Bsrc + (long long)r * ldbv + ((cc ^ (r & 7)) << 3),
                  Bs + buf * (BN * 128) + sub * (BN * 64) + ((wbase + g * 256) << 3));
        }
      }
    };
    auto compute5 = [&](int buf) {
#pragma unroll
      for (int sub = 0; sub < 2; sub++) {
#pragma unroll
        for (int kh = 0; kh < 2; kh++) {
          const int kc = kh * 4 + q;
          short8 afr[MI], bfr[NJ];
#pragma unroll
          for (int i = 0; i < MI; i++) {
            int row = wr * RM + i * 16 + mlow;
            afr[i] = *(const short8*)&As[buf * (BM * 128) + sub * (BM * 64) +
                                         (row * 8 + (kc ^ (row & 7))) * 8];
          }
#pragma unroll
          for (int j = 0; j < NJ; j++) {
            int row = wc * RN + j * 16 + mlow;
            bfr[j] = *(const short8*)&Bs[buf * (BN * 128) + sub * (BN * 64) +
                                         (row * 8 + (kc ^ (row & 7))) * 8];
          }
#pragma unroll
          for (int i = 0; i < MI; i++)
#pragma unroll
            for (int j = 0; j < NJ; j++)
              acc[i][j] = __builtin_amdgcn_mfma_f32_16x16x32_bf16(afr[i], bfr[j], acc[i][j], 0, 0, 0);
        }
      }
    };
    stage5(0, 0);
    stage5(1, 1);
    fence_bar<6>();  // retire super-step 0; step 1's 6 groups stay in flight
    for (int ki = 0; ki < ns; ki++) {
      if (ki + 2 < ns) stage5((ki + 2) % 3, ki + 2);
      compute5(ki % 3);
      if (ki + 1 < ns) {
        const int rem = ns - 1 - ki;
        if (rem >= 2) fence_bar<6>();
        else fence_bar<0>();
      }
    }
    __syncthreads();  // protect LDS reuse in epilogue
  } else if constexpr (MODE == 13) {
    // 3-deep B pipeline + 2-deep VALU-generated A; counted vmcnt(2) fences.
    const int nk = Kv >> 6;  // = 16
    agen_ld(0);
    stageAB(0, 0);
    if (nk > 1) stageAB(1, 64);
    agen_st(0);        // waits s2 loads (oldest) -> B tiles stay in flight
    fence13();         // B0 landed; B1 in flight
    for (int ki = 0; ki < nk; ki++) {
      if (ki + 1 < nk) agen_ld((ki + 1) << 6);
      if (ki + 2 < nk) stageAB((ki + 2) % 3, (ki + 2) << 6);
      if (ki + 1 < nk) agen_st((ki + 1) & 1);  // implicit s2-wait retires B(ki+1)
      compute_tile(ki & 1, ki % 3);
      fence13();
    }
  } else {
    for (int k0 = 0; k0 < Kv; k0 += 64) {
      stageAB(0, k0);
      __syncthreads();
      compute_tile(0, 0);
      __syncthreads();
    }
  }

  if constexpr (MODE == 3) {
    if (job4) {
      // full unscaled Abig: [l1u | L1L1u; l2u+b2 | L2L2u]; /Zgl done by adiv
      u16* abig = (u16*)Cf;
#pragma unroll
      for (int i = 0; i < MI; i++) {
#pragma unroll
        for (int j = 0; j < NJ; j++) {
#pragma unroll
          for (int rg = 0; rg < 4; rg++) {
            int r = r0 + wr * RM + i * 16 + q * 4 + rg;   // 0..255 (stack4 rows)
            int ncol = n0 + wc * RN + j * 16 + mlow;
            int blk = r >> 6, oo = r & 63;
            int drow = ((blk & 1) << 6) + oo;
            float v = acc[i][j][rg];
            if (blk < 2) v += aux3[drow];                 // rb2ext bias fold
            abig[(long long)z * (128 * 2048LL) + (long long)drow * 2048 +
                 (long long)(blk >> 1) * 1024 + ncol] = f2bf(v);
          }
        }
      }
    } else {
      const float* sqb = aux1 + (long long)z * NI;
#pragma unroll
      for (int i = 0; i < MI; i++) {
#pragma unroll
        for (int rg = 0; rg < 4; rg++) {
          int r = r0 + wr * RM + i * 16 + q * 4 + rg;
          float sqi = sqb[r];
          float rsum = 0.f;
#pragma unroll
          for (int j = 0; j < NJ; j++) {
            int ncol = n0 + wc * RN + j * 16 + mlow;
            float d2 = fmaxf(sqi + sqb[ncol] - 2.f * acc[i][j][rg], 0.f);
            float w = __expf(__expf(-d2 * (1.f / 128.f)) + (r == ncol ? 1.f : 0.f) - 2.f);
            Cb[(long long)z * bsC + (long long)r * ldc + ncol] = f2bf(w);
            rsum += w;
          }
          rsum += __shfl_xor(rsum, 1);
          rsum += __shfl_xor(rsum, 2);
          rsum += __shfl_xor(rsum, 4);
          rsum += __shfl_xor(rsum, 8);
          if (mlow == 0) atomicAdd(&Zout[(long long)z * NI + r], rsum);
        }
      }
    }
  } else if constexpr (MODE == 14) {
    // hT write + rank-1 bias (wcs=aux3 x emb2_b=aux1) + column dots w/ atta (aux2)
    float ps1 = 0.f, ps2 = 0.f;
#pragma unroll
    for (int i = 0; i < MI; i++) {
#pragma unroll
      for (int rg = 0; rg < 4; rg++) {
        int r = wr * RM + i * 16 + q * 4 + rg;  // r0 == 0
        int ncol = n0 + wc * RN + mlow;
        float v = acc[i][0][rg] + aux3[r] * aux1[ncol];
        Cb[(long long)z * bsC + (long long)r * ldc + ncol] = f2bf(v);
        ps1 = fmaf(v, aux2[r], ps1);
        ps2 = fmaf(v, aux2[64 + r], ps2);
      }
    }
    ps1 += __shfl_xor(ps1, 16); ps1 += __shfl_xor(ps1, 32);
    ps2 += __shfl_xor(ps2, 16); ps2 += __shfl_xor(ps2, 32);
    float* sred = (float*)As;  // s1: [32 cols][2 wr]; s2 at +64
    const int col = wc * RN + mlow;
    if (q == 0) { sred[col * 2 + wr] = ps1; sred[64 + col * 2 + wr] = ps2; }
    __syncthreads();
    if (tid < 32) {
      float v1 = sred[tid * 2] + sred[tid * 2 + 1];
      float v2 = sred[64 + tid * 2] + sred[64 + tid * 2 + 1];
      Cf[(long long)z * NI + n0 + tid] = v1;
      Zout[(long long)z * NI + n0 + tid] = v2;
      float mx = v2;
      for (int off = 1; off < 32; off <<= 1) mx = fmaxf(mx, __shfl_xor(mx, off));
      if (tid == 0) atomicMax((unsigned*)B2g + z, fkey(mx));
    }
  } else if constexpr (MODE == 13) {
    // ---- stage-1 finish: in-block softmax denominator (BM=32) ----
    float* zred = (float*)xa;            // [32][8]
    float* zinv = (float*)xa + 256;      // [32]
    zred[(tid >> 3) * 8 + (tid & 7)] = zp0;
    __syncthreads();
    if (tid < 32) {
      float sum = 0.f;
#pragma unroll
      for (int j = 0; j < 8; j++) sum += zred[tid * 8 + j];
      zinv[tid] = 1.f / sum;
    }
    __syncthreads();
    float zr[4];
#pragma unroll
    for (int rg = 0; rg < 4; rg++) zr[rg] = zinv[wr * 16 + q * 4 + rg];
    __syncthreads();  // all zinv reads done before xa overwrite
    // ---- x_att tile (relu, scaled) -> xa as A-fragments; uaiw -> Bs ----
#pragma unroll
    for (int j = 0; j < NJ; j++) {
#pragma unroll
      for (int rg = 0; rg < 4; rg++) {
        int row = wr * 16 + q * 4 + rg;
        int col = wc * RN + j * 16 + mlow;
        float v = fmaxf(acc[0][j][rg] * zr[rg], 0.f);
        xa[row * 72 + col] = f2bf(v);
      }
    }
#pragma unroll
    for (int s = 0; s < 2; s++) {
      int cid = tid + s * 256;
      int r = cid >> 3, cc = cid & 7;
      gload16(B2g + r * 64 + ((cc ^ (r & 7)) << 3),
              Bs + ((wbase + s * 256) << 3));
    }
    __syncthreads();
    // ---- stage-2: x_uai tile = xa @ uaiw^T (K=64) ----
    floatx4 acc2[2] = {};
#pragma unroll
    for (int kh = 0; kh < 2; kh++) {
      const int kc = kh * 4 + q;
      short8 a2 = *(const short8*)&xa[(wr * 16 + mlow) * 72 + kc * 8];
#pragma unroll
      for (int j = 0; j < 2; j++) {
        int orow = wc * 32 + j * 16 + mlow;
        short8 b2 = *(const short8*)&Bs[(orow * 8 + (kc ^ (orow & 7))) * 8];
        acc2[j] = __builtin_amdgcn_mfma_f32_16x16x32_bf16(a2, b2, acc2[j], 0, 0, 0);
      }
    }
#pragma unroll
    for (int rg = 0; rg < 4; rg++) {
      int row = r0 + wr * 16 + q * 4 + rg;
      float sqp = 0.f;
#pragma unroll
      for (int j = 0; j < 2; j++) {
        int o = wc * 32 + j * 16 + mlow;
        float v = acc2[j][rg] + aux1[o];
        Cb[(long long)z * bsC + (long long)row * ldc + o] = f2bf(v);
        sqp = fmaf(v, v, sqp);
      }
      sqp += __shfl_xor(sqp, 1);
      sqp += __shfl_xor(sqp, 2);
      sqp += __shfl_xor(sqp, 4);
      sqp += __shfl_xor(sqp, 8);
      if (mlow == 0) atomicAdd(&Zout[(long long)z * NI + row], sqp);
    }
  } else if constexpr (MODE == 5) {
    // rank-1: rb2ext (aux3) x cs2 (aux1) + rl2ext (aux4) x v2 (aux2); bf16 out;
    // LN stats from fp32 values
    float ts = 0.f, tss = 0.f;
#pragma unroll
    for (int i = 0; i < MI; i++) {
#pragma unroll
      for (int j = 0; j < NJ; j++) {
#pragma unroll
        for (int rg = 0; rg < 4; rg++) {
          int r = r0 + wr * RM + i * 16 + q * 4 + rg;
          int ncol = n0 + wc * RN + j * 16 + mlow;
          float v = acc[i][j][rg];
          v += aux3[r] * aux1[ncol] + aux4[r] * aux2[ncol];
          Cb[(long long)z * bsC + (long long)r * ldc + ncol] = f2bf(v);
          ts += v;
          tss = fmaf(v, v, tss);
        }
      }
    }
    // block-level LN partial stats -> atomics; half = r-tile (rows 0-63 xn, 64-127 ft)
    float* red = (float*)As;  // 512 floats
    red[tid] = ts; red[256 + tid] = tss;
    __syncthreads();
    for (int st = 128; st > 0; st >>= 1) {
      if (tid < st) { red[tid] += red[tid + st]; red[256 + tid] += red[256 + tid + st]; }
      __syncthreads();
    }
    if (tid == 0) {
      const int half = r0 >> 6;
      atomicAdd(&Zout[z * 2 + half], red[0]);
      atomicAdd(&Zout[32 + z * 2 + half], red[256]);
    }
  } else {
    // MODE 15 (GEMM jobs) element-wise epilogue
#pragma unroll
    for (int i = 0; i < MI; i++) {
#pragma unroll
      for (int j = 0; j < NJ; j++) {
#pragma unroll
        for (int rg = 0; rg < 4; rg++) {
          int r = r0 + wr * RM + i * 16 + q * 4 + rg;
          int ncol = n0 + wc * RN + j * 16 + mlow;
          Cb[cboff + (long long)r * ldc + ncol] = f2bf(acc[i][j][rg]);
        }
      }
    }
  }
}

// ---- adiv: Abig W-half /= Zgl (K-indexed) in place. 2M elements; replaces the
// 16x-larger B-side divide that round-7/8 did per K-iteration in mode 5. ----
__global__ __launch_bounds__(256) void adiv(u16* __restrict__ abig,
                                            const float* __restrict__ Zgl)
{
  const int bid = blockIdx.x;            // 1024: z = bid>>6, row-pair = (bid&63)*2
  const int z = bid >> 6;
  const int r = (bid & 63) * 2;
  const int t = threadIdx.x;
  const int c = t * 4;
  const float4 zv = *(const float4*)(Zgl + (long long)z * NI + c);
  const float i0 = __builtin_amdgcn_rcpf(zv.x);
  const float i1 = __builtin_amdgcn_rcpf(zv.y);
  const float i2 = __builtin_amdgcn_rcpf(zv.z);
  const float i3 = __builtin_amdgcn_rcpf(zv.w);
  u16* base = abig + (long long)z * (128 * 2048LL) + (long long)r * 2048 + c;
#pragma unroll
  for (int rr = 0; rr < 2; rr++) {
    u16* p = base + (long long)rr * 2048;
    uint2 v = *(uint2*)p;
    u16 o[4];
    o[0] = f2bf(bf2f((u16)(v.x & 0xffff)) * i0);
    o[1] = f2bf(bf2f((u16)(v.x >> 16)) * i1);
    o[2] = f2bf(bf2f((u16)(v.y & 0xffff)) * i2);
    o[3] = f2bf(bf2f((u16)(v.y >> 16)) * i3);
    *(uint2*)p = *(uint2*)o;
  }
}

// ---- lap_rowsum + zero-init: blocks <2048 do dr[k][i]; rest zero the atomic region ----
__global__ __launch_bounds__(256) void lap_rowsum(const float* __restrict__ gd,
                                                  float* __restrict__ dr,
                                                  float* __restrict__ zero)
{
  if (blockIdx.x >= 2048) {
    int i = (blockIdx.x - 2048) * 256 + threadIdx.x;
    if (i < ZERON) zero[i] = 0.f;
    return;
  }
  const int ki = blockIdx.x;
  const float* row = gd + (long long)ki * NI;
  float s = 0.f;
  for (int j = threadIdx.x; j < NI; j += 256) s += row[j];
  __shared__ float red[256];
  red[threadIdx.x] = s; __syncthreads();
  for (int st = 128; st > 0; st >>= 1) {
    if (threadIdx.x < st) red[threadIdx.x] += red[threadIdx.x + st];
    __syncthreads();
  }
  if (threadIdx.x == 0) dr[ki] = rsqrtf(red[0] + 1.f);
}

// ---------------- mega_prep: blockIdx-range dispatch of all prep work ----------------
// [0,98)       small weights | [98,1122) emb2_w cast (float4) |
// [1122,1378)  convT | [1378,2402) g2t (float4) | [2402,3426) g1 | [3426,4450) cs1
__global__ __launch_bounds__(256) void mega_prep(
    const float* __restrict__ l1w, const float* __restrict__ l2w,
    const float* __restrict__ l2b, const float* __restrict__ uaiw,
    const float* __restrict__ attW,
    u16* __restrict__ stack4, float* __restrict__ rb2ext, float* __restrict__ rl2ext,
    u16* __restrict__ uaiw_bf, u16* __restrict__ attwT_bf, float* __restrict__ wcs,
    const float* __restrict__ emb2w, u16* __restrict__ emb2w_bf,
    const float* __restrict__ x, const float* __restrict__ ew,
    const float* __restrict__ eb, u16* __restrict__ h0aT,
    const float* __restrict__ gd, const float* __restrict__ dsum,
    u16* __restrict__ g2t, u16* __restrict__ g1,
    float* __restrict__ cs1)
{
  __shared__ float sm[1092];
  const int bid = blockIdx.x;
  const int t = threadIdx.x;
  if (bid < 98) {
    const int gid = bid * 256 + t;
    if (gid < 4096) {
      stack4[gid] = f2bf(l1w[gid]);
    } else if (gid < 8192) {
      stack4[gid] = f2bf(l2w[gid - 4096]);
    } else if (gid < 12288) {
      int tt = gid - 8192, o = tt >> 6, m = tt & 63;
      float s = 0.f;
      for (int c = 0; c < 64; c++) s = fmaf(l1w[o * 64 + c], l1w[c * 64 + m], s);
      stack4[gid] = f2bf(s);
    } else if (gid < 16384) {
      int tt = gid - 12288, o = tt >> 6, m = tt & 63;
      float s = 0.f;
      for (int c = 0; c < 64; c++) s = fmaf(l2w[o * 64 + c], l2w[c * 64 + m], s);
      stack4[gid] = f2bf(s);
    } else if (gid < 16512) {
      int r = gid - 16384;
      rb2ext[r] = (r < 64) ? 0.f : l2b[r - 64];
    } else if (gid < 16640) {
      int r = gid - 16512;
      float v = 0.f;
      if (r >= 64) { int o = r - 64; for (int c = 0; c < 64; c++) v = fmaf(l2w[o * 64 + c], l2b[c], v); }
      rl2ext[r] = v;
    } else if (gid < 20736) {
      uaiw_bf[gid - 16640] = f2bf(uaiw[gid - 16640]);
    } else if (gid < 24832) {
      int idx = gid - 20736;                 // attwT[c][e] = attW[e][c]
      int c = idx >> 6, e = idx & 63;
      attwT_bf[idx] = f2bf(attW[e * 64 + c]);
    } else if (gid < 24896) {
      int c = gid - 24832;                   // wcs[c] = sum_e attW[e][c]
      float s = 0.f;
      for (int e = 0; e < 64; e++) s += attW[e * 64 + c];
      wcs[c] = s;
    }
  } else if (bid < 1122) {
    const long long i = (long long)(bid - 98) * 1024 + t * 4;
    float4 v = *(const float4*)(emb2w + i);
    u16 o4[4] = {f2bf(v.x), f2bf(v.y), f2bf(v.z), f2bf(v.w)};
    *(uint2*)(emb2w_bf + i) = *(const uint2*)o4;
  } else if (bid < 1378) {
    // convT: h0aT[b][n][e], 64 n per block, 4 threads/n each doing 16 e
    const int sub = bid - 1122;
    const int b = sub >> 4;
    const int nc = (sub & 15) * 64;
    float* we = sm;          // [64][16]
    float* be = sm + 1024;   // [64]
    for (int i = t; i < 1024; i += 256) we[i] = ew[i];
    if (t < 64) be[t] = eb[t];
    __syncthreads();
    const int n = nc + (t >> 2);
    const int e0 = (t & 3) * 16;
    const float* xb = x + (long long)b * CI * NI + n;
    float xv[16];
#pragma unroll
    for (int c = 0; c < CI; c++) xv[c] = xb[(long long)c * NI];
    u16 out16[16];
#pragma unroll
    for (int ee = 0; ee < 16; ee++) {
      const int e = e0 + ee;
      float a = be[e];
#pragma unroll
      for (int c = 0; c < CI; c++) a = fmaf(xv[c], we[e * 16 + c], a);
      out16[ee] = f2bf(lrelu01(a));
    }
    u16* dst = h0aT + (long long)b * S1 + (long long)n * 64 + e0;
    *(uint4*)dst = *(uint4*)out16;
    *(uint4*)(dst + 8) = *(uint4*)(out16 + 8);
  } else if (bid < 2402) {
    const int m = bid - 1378;
    const int j = t * 4;
    const float* d = dsum + NI;
    float4 g = *(const float4*)(gd + NN2 + (long long)m * NI + j);
    float dm = d[m];
    float4 dj = *(const float4*)(d + j);
    u16 o4[4];
    o4[0] = f2bf((g.x + (m == j     ? 1.f : 0.f)) * dm * dj.x);
    o4[1] = f2bf((g.y + (m == j + 1 ? 1.f : 0.f)) * dm * dj.y);
    o4[2] = f2bf((g.z + (m == j + 2 ? 1.f : 0.f)) * dm * dj.z);
    o4[3] = f2bf((g.w + (m == j + 3 ? 1.f : 0.f)) * dm * dj.w);
    *(uint2*)(g2t + (long long)m * NI + j) = *(const uint2*)o4;
  } else if (bid < 3426) {
    const int sub = bid - 2402;
    const int bx = (sub & 31) * 32, by = (sub >> 5) * 32;
    const int lx = t & 31, ly = t >> 5;  // 32x8
    float* tile = sm;                    // 32x33
    for (int yy = ly; yy < 32; yy += 8)
      tile[yy * 33 + lx] = gd[(long long)(by + yy) * NI + bx + lx];
    __syncthreads();
    for (int yy = ly; yy < 32; yy += 8) {
      const int i = bx + yy, j = by + lx;
      float v = (tile[lx * 33 + yy] + (i == j ? 1.f : 0.f)) * dsum[i] * dsum[j];
      g1[(long long)i * NI + j] = f2bf(v);
    }
  } else {
    const int n = bid - 3426;
    float s = 0.f;
    for (int i = t; i < NI; i += 256) s = fmaf(gd[(long long)n * NI + i], dsum[i], s);
    float* red = sm;
    red[t] = s; __syncthreads();
    for (int st = 128; st > 0; st >>= 1) {
      if (t < st) red[t] += red[t + st];
      __syncthreads();
    }
    if (t == 0) cs1[n] = dsum[n] * (red[0] + dsum[n]);
  }
}

// ---- LayerNorm apply + GELU + final gating; 512 threads (8 waves) for TLP ----
__global__ __launch_bounds__(512) void ln_final_t(const u16* __restrict__ T,
                                                  const float* __restrict__ stats,
                                                  const float* __restrict__ lnw,
                                                  const float* __restrict__ lnb,
                                                  const float* __restrict__ ct,
                                                  const u16* __restrict__ xuT,
                                                  float* __restrict__ outp)
{
  __shared__ float xs[64 * 65];
  const int blk = blockIdx.x;
  const int b = blk >> 4;
  const int n0 = (blk & 15) << 6;
  const int t = threadIdx.x;
  const int tc = t & 63, tr = t >> 6;  // tr in [0,8)
#pragma unroll
  for (int i = 0; i < 8; i++) {
    int nn = i * 8 + tr;
    xs[tc * 65 + nn] = bf2f(xuT[((long long)b << 16) + (long long)(n0 + nn) * 64 + tc]);
  }
  __syncthreads();
  const float inv_n = 1.f / 65536.f;
  const float m0 = stats[b * 2] * inv_n;
  const float m1 = stats[b * 2 + 1] * inv_n;
  const float rs0 = rsqrtf(fmaxf(stats[32 + b * 2] * inv_n - m0 * m0, 0.f) + 1e-5f);
  const float rs1 = rsqrtf(fmaxf(stats[32 + b * 2 + 1] * inv_n - m1 * m1, 0.f) + 1e-5f);
#pragma unroll
  for (int j = 0; j < 8; j++) {
    const int c = j * 8 + tr;
    const int n = n0 + tc;
    const int rem = c * NI + n;
    const long long toff = (long long)b * S2 + rem;
    const float t0 = bf2f(T[toff]);
    const float t1 = bf2f(T[toff + S1]);
    const float w = lnw[rem], bb = lnb[rem];
    const float xn = (t0 - m0) * rs0 * w + bb;
    float ft = (t1 - m1) * rs1 * w + bb;
    ft = 0.5f * ft * (1.f + erff(ft * 0.70710678118654752f));
    const float u = xs[c * 65 + tc];
    const long long oidx = ((long long)b << 16) + rem;
    const float cn = fmaf(ft, ct[oidx] - xn, xn);
    const float el = cn > 0.f ? cn : expm1f(cn);
    outp[oidx] = fmaf(ft, el - u, u);
    outp[BCN + oidx] = cn;
  }
}

extern "C" void kernel_launch(void* const* d_in, const int* in_sizes, int n_in,
                              void* d_out, int out_size, void* d_ws, size_t ws_size,
                              hipStream_t stream)
{
  (void)in_sizes; (void)n_in; (void)out_size; (void)ws_size;
  const float* x      = (const float*)d_in[0];
  const float* ct     = (const float*)d_in[1];
  const float* gdata  = (const float*)d_in[2];
  const float* emb_w  = (const float*)d_in[3];
  const float* emb_b  = (const float*)d_in[4];
  const float* emb2_w = (const float*)d_in[5];
  const float* emb2_b = (const float*)d_in[6];
  const float* att_W  = (const float*)d_in[7];
  const float* att_a  = (const float*)d_in[8];
  // d_in[9] att_GL unused: softmax(relu(GL GL^T)) > 0 everywhere -> mask is a no-op
  const float* uai_w  = (const float*)d_in[10];
  const float* uai_b  = (const float*)d_in[11];
  const float* lin1_w = (const float*)d_in[12];
  const float* lin2_w = (const float*)d_in[13];
  const float* lin2_b = (const float*)d_in[14];
  const float* ln_w   = (const float*)d_in[15];
  const float* ln_b   = (const float*)d_in[16];
  float* outp = (float*)d_out;

  float* ws = (float*)d_ws;
  long long o = 0;
  auto af = [&](long long n) { float* p = ws + o; o += (n + 63) & ~63LL; return p; };
  auto au = [&](long long n) { return (u16*)af((n + 1) / 2); };

  float* s1      = af(BNv);
  float* s2      = af(BNv);
  float* dsum    = af(2 * NI);
  float* cs1v    = af(NI);
  float* cs2v    = af(NI);
  float* v2v     = af(NI);
  float* rb2ext  = af(128);
  float* rl2ext  = af(128);
  float* wcs     = af(64);
  // contiguous zero-init region: Zgl, sqv, stats(64), s2mU(16)
  float* zeroreg = af(ZERON);
  float* Zgl     = zeroreg;
  float* sqv     = zeroreg + BNv;
  float* stats   = zeroreg + 2 * BNv;
  unsigned* s2mU = (unsigned*)(stats + 64);
  u16* Tacc      = au(S2 * BATCH);   // bf16
  u16* emb2w_bf  = au(NN2);
  u16* h0aTb     = au(S1 * BATCH);   // [b][n][e]
  u16* ybf       = au(S1 * BATCH);   // y = attW^T @ h0a, [b][c][n]
  u16* hTb       = au(S1 * BATCH);   // [b][c][n]
  u16* xuaiTb    = au(S1 * BATCH);   // [b][n][c]
  u16* g1b       = au(NN2);
  u16* g2tb      = au(NN2);
  u16* G12b      = au(NN2);
  u16* Abig      = au((long long)BATCH * 128 * 2048);
  u16* stack4    = au(256 * 64);
  u16* uaiw_bf   = au(CE * CE);
  u16* attwT_bf  = au(CE * CE);
  u16* bigW      = au(BNN);  // 32 MB: gram W (att-p computed on the fly)

  // lap_rowsum also zero-inits the atomic region (no separate memset node)
  lap_rowsum<<<2048 + (ZERON + 255) / 256, 256, 0, stream>>>(gdata, dsum, zeroreg);

  mega_prep<<<4450, 256, 0, stream>>>(
      lin1_w, lin2_w, lin2_b, uai_w, att_W,
      stack4, rb2ext, rl2ext, uaiw_bf, attwT_bf, wcs,
      emb2_w, emb2w_bf, x, emb_w, emb_b, h0aTb,
      gdata, dsum, g2tb, g1b, cs1v);

  // merged dispatch: [0,512) G12t=(g1@g2)^T | [512,1536) csv2 rows |
  // [1536,2048) y = attW^T @ h0a (independent chains joined to fill the machine)
  mgemm<32, 64, 15><<<2048, 256, 0, stream>>>(
      g2tb, g1b, attwT_bf, NI, NI, NI, NI, 0, (long long)(ybf - G12b),
      cs2v, G12b, NI, 0, cs1v, dsum + NI, gdata + NN2, (const float*)h0aTb, v2v);

  // hT[b][c][n'] = y @ emb2w^T + wcs (x) emb2_b; epilogue computes s1/s2/s2max
  mgemm<64, 32, 14><<<512, 256, 0, stream>>>(
      ybf, emb2w_bf, (const u16*)s2mU, NI, NI, NI, NI, S1, 0,
      s1, hTb, NI, S1, emb2_b, att_a, wcs, nullptr, s2);

  // fused two-stage: x_att = relu((p@h)/Z) then x_uai = x_att @ uaiw^T + uai_b
  mgemm<32, 64, 13><<<512, 256, 0, stream>>>(
      hTb, hTb, uaiw_bf, NI, NI, NI, NI, 0, S1,
      nullptr, xuaiTb, CE, S1, uai_b, s1, s2, (const float*)s2mU, sqv);

  // gram/gl weights (4096 XCD-grouped blocks) + FULL unscaled Abig (1024 blocks)
  mgemm<64, 64, 3><<<5120, 256, 0, stream>>>(
      xuaiTb, xuaiTb, nullptr, CE, CE, CE, CE, S1, S1,
      (float*)Abig, bigW, NI, NN2, sqv, (const float*)stack4, rb2ext, nullptr, Zgl);

  // Abig W-half /= Zgl (one-shot; removes the divide from mode 5's hot loop)
  adiv<<<1024, 256, 0, stream>>>(Abig, Zgl);

  // Tacc(bf16) = Abig @ [W ; G12t] + b2 (x) cs2 + (L2 b2) (x) v2, + LN stats;
  // BK=128 super-steps (8 MFMA/barrier), z%8==xcd L2-warm bigW mapping
  mgemm<64, 32, 5><<<1024, 256, 0, stream>>>(
      Abig, bigW, G12b, NI, 2 * NI, 2048, NI, (long long)128 * 2048, NN2,
      nullptr, Tacc, NI, S2, cs2v, v2v, rb2ext, rl2ext, stats);

  ln_final_t<<<256, 512, 0, stream>>>(Tacc, stats, ln_w, ln_b, ct, xuaiTb, outp);
}

// Round 10
// 219.280 us; speedup vs baseline: 1.0276x; 1.0276x over previous
//
#include <hip/hip_runtime.h>
#include <math.h>

typedef unsigned short u16;
typedef __attribute__((ext_vector_type(8))) short short8;
typedef __attribute__((ext_vector_type(4))) float floatx4;

constexpr int BATCH = 16;
constexpr int NI = 1024;
constexpr int CE = 64;
constexpr int CI = 16;
constexpr long long NN2  = (long long)NI * NI;          // 1M
constexpr long long BCN  = (long long)BATCH * CE * NI;  // 1M
constexpr long long BNv  = (long long)BATCH * NI;       // 16K
constexpr long long BNN  = (long long)BATCH * NI * NI;  // 16M
constexpr long long S1 = (long long)CE * NI;            // 65536
constexpr long long S2 = 2 * S1;                        // 131072
constexpr int ZERON = (int)(2 * BNv + 80);              // zero-init region elements

__device__ __forceinline__ float lrelu01(float x) { return x > 0.f ? x : 0.01f * x; }

__device__ __forceinline__ u16 f2bf(float f) {
  unsigned u = __builtin_bit_cast(unsigned, f);
  return (u16)((u + 0x7fffu + ((u >> 16) & 1u)) >> 16);  // RNE
}
__device__ __forceinline__ float bf2f(u16 h) {
  unsigned u = ((unsigned)h) << 16;
  return __builtin_bit_cast(float, u);
}
// monotonic uint key for float atomicMax (zero-init safe: real-float keys > 0)
__device__ __forceinline__ unsigned fkey(float f) {
  unsigned u = __builtin_bit_cast(unsigned, f);
  return (u & 0x80000000u) ? ~u : (u | 0x80000000u);
}
__device__ __forceinline__ float funkey(unsigned k) {
  unsigned u = (k & 0x80000000u) ? (k & 0x7fffffffu) : ~k;
  return __builtin_bit_cast(float, u);
}

// async global->LDS, 16B per lane. LDS dest is wave-uniform base + lane*16;
// swizzle is achieved by pre-swizzling the per-lane GLOBAL source (m173 pattern).
__device__ __forceinline__ void gload16(const u16* g, u16* l) {
  __builtin_amdgcn_global_load_lds(
      (const __attribute__((address_space(1))) void*)g,
      (__attribute__((address_space(3))) void*)l, 16, 0, 0);
}

// mode-13 fence: B(ki+2) (2 gload groups) stays in flight across the barrier
__device__ __forceinline__ void fence13() {
  __builtin_amdgcn_sched_barrier(0);
  asm volatile("s_waitcnt vmcnt(2) lgkmcnt(0)" ::: "memory");
  __builtin_amdgcn_s_barrier();
  __builtin_amdgcn_sched_barrier(0);
}

// counted-vmcnt fence: wait until <= N vector-mem groups outstanding, then barrier.
// All waves stage in lockstep, so post-barrier every wave's older tiles landed.
template<int N>
__device__ __forceinline__ void fence_bar() {
  __builtin_amdgcn_sched_barrier(0);
  if constexpr (N == 0) asm volatile("s_waitcnt vmcnt(0)" ::: "memory");
  else if constexpr (N == 1) asm volatile("s_waitcnt vmcnt(1)" ::: "memory");
  else if constexpr (N == 2) asm volatile("s_waitcnt vmcnt(2)" ::: "memory");
  else if constexpr (N == 3) asm volatile("s_waitcnt vmcnt(3)" ::: "memory");
  else if constexpr (N == 4) asm volatile("s_waitcnt vmcnt(4)" ::: "memory");
  else if constexpr (N == 6) asm volatile("s_waitcnt vmcnt(6)" ::: "memory");
  else asm volatile("s_waitcnt vmcnt(0)" ::: "memory");
  __builtin_amdgcn_s_barrier();
  __builtin_amdgcn_sched_barrier(0);
}

// ================= MFMA TN GEMM: C[r][m] = sum_k A[r][k] * Bt[m][k] ==============
// A, Bt bf16 row-major K-contiguous. BK=64, XOR-swizzled 16B chunks in LDS.
// MODE: 3 flat grid: [0,4096) gram exp + rowsum (XCD-grouped by z) |
//          [4096,5120) FULL unscaled Abig = [l1u+0|L1L1u; l2u+b2|L2L2u] (no Zgl dep)|
//       5 BM=128xBN=64 (m97-shape: 16 MFMA + 12 ds_read per K-step per wave),
//          depth-3 counted vmcnt(6), dual-B, A pre-divided by Z (adiv),
//          z%8==xcd L2-warm bigW; rank-1 + per-half LN stats epilogue |
//       13 A = attention-p on the fly, 3-deep B pipe w/ counted vmcnt |
//       14 hT direct: +rank-1 + per-column s1/s2 dots + s2max, XCD flat grid |
//       15 flat grid: [0,512) G12 GEMM | [512,1536) csv2 rows | [1536,2048) y-GEMM
template<int BM, int BN, int MODE>
__global__ __launch_bounds__(256) void mgemm(
    const u16* __restrict__ Ag, const u16* __restrict__ B1g, const u16* __restrict__ B2g,
    int K1, int K, int lda, int ldb, long long bsA, long long bsB1,
    float* __restrict__ Cf, u16* __restrict__ Cb, int ldc, long long bsC,
    const float* __restrict__ aux1, const float* __restrict__ aux2,
    const float* __restrict__ aux3, const float* __restrict__ aux4,
    float* __restrict__ Zout)
{
  constexpr int RM = BM / 2, RN = BN / 2, MI = RM / 16, NJ = RN / 16;
  constexpr bool PIPE3 = (MODE == 5 || MODE == 14 || MODE == 15);
  constexpr int NBB = PIPE3 ? 3 : (MODE == 13 ? 3 : 1);
  constexpr int NBA = PIPE3 ? 3 : (MODE == 13 ? 2 : 1);
  constexpr int NLA = (BM * 8) / 256;  // per-thread A gload chunks per 64-K-tile
  constexpr int NLB = (BN * 8) / 256;
  constexpr int L = (NLA + NLB);       // gload groups per PIPE3 stage
  __shared__ __align__(16) u16 As[NBA * BM * 64];
  __shared__ __align__(16) u16 Bs[NBB * BN * 64];
  __shared__ __align__(16) u16 xa[MODE == 13 ? 32 * 72 : 1];  // stage-2 A tile (padded)
  const int tid = threadIdx.x;
  int z, n0, r0, job15 = 0;
  bool job4 = false;
  long long cboff = 0;
  if constexpr (MODE == 15) {
    const int id = blockIdx.x;
    if (id >= 512 && id < 1536) {
      // csv2: cs2[m]=colsum g2; v2[m]=(cs1@g2)[m].  aux3=gdata2raw, aux2=d2, aux1=cs1
      const int m = id - 512;
      float s = 0.f, sv = 0.f;
      for (int n = tid; n < NI; n += 256) {
        float g = aux3[(long long)m * NI + n] * aux2[n];
        s += g;
        sv = fmaf(g, aux1[n], sv);
      }
      float* r1 = (float*)As;
      float* r2 = (float*)As + 256;
      r1[tid] = s; r2[tid] = sv; __syncthreads();
      for (int st = 128; st > 0; st >>= 1) {
        if (tid < st) { r1[tid] += r1[tid + st]; r2[tid] += r2[tid + st]; }
        __syncthreads();
      }
      if (tid == 0) {
        float dm = aux2[m];
        Cf[m] = dm * (r1[0] + dm);
        Zout[m] = dm * (r2[0] + dm * aux1[m]);
      }
      return;
    }
    if (id >= 1536) {                       // y-GEMM: y = attwT @ h0a
      const int id2 = id - 1536;
      job15 = 2;
      z = id2 >> 5; r0 = (id2 & 1) * BM; n0 = ((id2 >> 1) & 15) * BN;
    } else {
      z = 0; n0 = (id & 15) * BN; r0 = (id >> 4) * BM;
    }
  } else if constexpr (MODE == 5) {
    // 256 blocks, 1 per CU. z%8 == xcd matches mode-3's bigW placement (2 z per
    // XCD = 4 MB L2); 16 n-blocks of one z share its 512 KB A-panel on-XCD.
    const int id = blockIdx.x;
    const int xcd = id & 7, idx = id >> 3;             // idx 0..31
    z = (idx & 1) * 8 + xcd;
    r0 = 0;
    n0 = (idx >> 1) * BN;
  } else if constexpr (MODE == 3) {
    const int id = blockIdx.x;
    if (id < 4096) {
      const int xcd = id & 7, idx = id >> 3;
      z = (idx >> 8) * 8 + xcd;              // 2 z's per XCD
      const int g = idx & 255;
      n0 = (g & 15) * 64; r0 = ((g >> 4) & 15) * 64;
    } else {                                 // full unscaled Abig (1024 blocks)
      const int t4 = id - 4096;              // 0..1023
      job4 = true;
      z = t4 >> 6;
      const int g = t4 & 63;
      r0 = (g >> 4) * 64;                    // yblk 0..3 -> stack4 rows
      n0 = (g & 15) * 64;
    }
  } else if constexpr (MODE == 13 || MODE == 14) {
    const int id = blockIdx.x;               // 512 blocks flat
    const int xcd = id & 7, idx = id >> 3;
    z = (idx >> 5) * 8 + xcd;                // 2 z's per XCD
    if constexpr (MODE == 13) { r0 = (idx & 31) * BM; n0 = 0; }
    else { n0 = (idx & 31) * BN; r0 = 0; }
  } else {
    z = blockIdx.z; n0 = blockIdx.x * BN; r0 = blockIdx.y * BM;
  }
  int Kv = K, K1v = K1, ldav = lda, ldbv = ldb;
  const u16 *Ab, *Bb1;
  if constexpr (MODE == 15) {
    if (job15 == 2) {
      Kv = 64; K1v = 128; ldav = 64; ldbv = 64;
      Ab = B2g + (long long)r0 * 64;                               // attwT_bf
      Bb1 = (const u16*)aux4 + (long long)z * S1 + (long long)n0 * 64;  // h0aT
      cboff = bsB1 + (long long)z * S1;                            // -> ybf
    } else {
      Ab = Ag + (long long)r0 * lda;
      Bb1 = B1g + (long long)n0 * ldb;
    }
  } else {
    Ab = Ag + (long long)z * bsA + (long long)r0 * ldav;
    Bb1 = B1g + (long long)z * bsB1 + (long long)n0 * ldbv;
    if constexpr (MODE == 3) {
      if (job4) Ab = ((const u16*)aux2) + (long long)r0 * 64;      // stack4 rows
    }
  }
  const int lane = tid & 63;
  const int wid = tid >> 6;
  const int wr = wid >> 1, wc = wid & 1;
  const int q = lane >> 4, mlow = lane & 15;
  const int wbase = tid & ~63;  // wave-uniform

  floatx4 acc[MI][NJ] = {};
  float zp0 = 0.f;  // MODE13 row p-sum (BM=32 -> single chunk/thread)

  // MODE13 per-thread row constants (k0-independent)
  float s1r_13 = 0.f, mr_13 = 0.f;
  const float* s2z_13 = nullptr;
  float4 sa, sb;  // MODE13 prefetched s2 values
  if constexpr (MODE == 13) {
    const float* s1z = aux2 + (long long)z * NI;
    s2z_13 = aux3 + (long long)z * NI;
    const float mb = funkey(((const unsigned*)aux4)[z]);
    s1r_13 = s1z[r0 + (tid >> 3)];
    mr_13 = lrelu01(s1r_13 + mb);
  }

  // ---- staging: global -> LDS (async), source pre-swizzled, LDS linear ----
  auto stageAB = [&](int buf, int k0) {
    if constexpr (MODE != 13) {
      const u16* Asrc = Ab + k0;
#pragma unroll
      for (int s = 0; s < NLA; s++) {
        int cid = tid + s * 256;
        int r = cid >> 3, cc = cid & 7;
        gload16(Asrc + (long long)r * ldav + ((cc ^ (r & 7)) << 3),
                As + buf * (BM * 64) + ((wbase + s * 256) << 3));
      }
    }
    const u16* Bsrc = (k0 < K1v) ? (Bb1 + k0)
                                 : (B2g + (long long)n0 * ldbv + (k0 - K1v));
#pragma unroll
    for (int s = 0; s < NLB; s++) {
      int cid = tid + s * 256;
      int r = cid >> 3, cc = cid & 7;
      gload16(Bsrc + (long long)r * ldbv + ((cc ^ (r & 7)) << 3),
              Bs + buf * (BN * 64) + ((wbase + s * 256) << 3));
    }
  };

  // ---- MODE13 A-tile gen, split: issue s2 loads FIRST (older than B gloads,
  // so the compiler's wait for sa/sb retires older B tiles but leaves the
  // just-issued B prefetch in flight) ----
  auto agen_ld = [&](int k0) {
    const float* sp = s2z_13 + k0 + (tid & 7) * 8;
    sa = *(const float4*)sp;
    sb = *(const float4*)(sp + 4);
  };
  auto agen_st = [&](int buf) {
    int r = tid >> 3, craw = tid & 7;
    float p0 = __expf(lrelu01(s1r_13 + sa.x) - mr_13);
    float p1 = __expf(lrelu01(s1r_13 + sa.y) - mr_13);
    float p2 = __expf(lrelu01(s1r_13 + sa.z) - mr_13);
    float p3 = __expf(lrelu01(s1r_13 + sa.w) - mr_13);
    float p4 = __expf(lrelu01(s1r_13 + sb.x) - mr_13);
    float p5 = __expf(lrelu01(s1r_13 + sb.y) - mr_13);
    float p6 = __expf(lrelu01(s1r_13 + sb.z) - mr_13);
    float p7 = __expf(lrelu01(s1r_13 + sb.w) - mr_13);
    zp0 += p0 + p1 + p2 + p3 + p4 + p5 + p6 + p7;
    uint4 v;
    v.x = (unsigned)f2bf(p0) | ((unsigned)f2bf(p1) << 16);
    v.y = (unsigned)f2bf(p2) | ((unsigned)f2bf(p3) << 16);
    v.z = (unsigned)f2bf(p4) | ((unsigned)f2bf(p5) << 16);
    v.w = (unsigned)f2bf(p6) | ((unsigned)f2bf(p7) << 16);
    *(uint4*)&As[buf * (BM * 64) + (r * 8 + (craw ^ (r & 7))) * 8] = v;
  };

  auto compute_tile = [&](int bufA, int bufB) {
#pragma unroll
    for (int kh = 0; kh < 2; kh++) {
      const int kc = kh * 4 + q;
      short8 afr[MI], bfr[NJ];
#pragma unroll
      for (int i = 0; i < MI; i++) {
        int row = wr * RM + i * 16 + mlow;
        afr[i] = *(const short8*)&As[bufA * (BM * 64) + (row * 8 + (kc ^ (row & 7))) * 8];
      }
#pragma unroll
      for (int j = 0; j < NJ; j++) {
        int row = wc * RN + j * 16 + mlow;
        bfr[j] = *(const short8*)&Bs[bufB * (BN * 64) + (row * 8 + (kc ^ (row & 7))) * 8];
      }
#pragma unroll
      for (int i = 0; i < MI; i++)
#pragma unroll
        for (int j = 0; j < NJ; j++)
          acc[i][j] = __builtin_amdgcn_mfma_f32_16x16x32_bf16(afr[i], bfr[j], acc[i][j], 0, 0, 0);
    }
  };

  if constexpr (PIPE3) {
    // 3-deep pipeline, counted vmcnt: tiles ki+1..ki+2 stay in flight.
    const int nk = Kv >> 6;
#pragma unroll
    for (int p = 0; p < 2; p++) {
      int kk = (p < nk) ? p : (nk - 1);   // clamp for short-K jobs (no OOB)
      stageAB(p, kk << 6);
    }
    fence_bar<L>();  // retire tile 0 everywhere
    int cur = 0, stg = 2;
    for (int ki = 0; ki < nk; ki++) {
      if (ki + 2 < nk) stageAB(stg, (ki + 2) << 6);
      compute_tile(cur, cur);
      if (ki + 1 < nk) {
        const int rem = nk - 1 - ki;
        const int u = (rem < 2) ? rem : 2;
        if (u == 2) fence_bar<L>();
        else fence_bar<0>();
      }
      cur++; if (cur == NBB) cur = 0;
      stg++; if (stg == NBB) stg = 0;
    }
    __syncthreads();  // drain + protect LDS reuse in epilogues
  } else if constexpr (MODE == 13) {
    // 3-deep B pipeline + 2-deep VALU-generated A; counted vmcnt(2) fences.
    const int nk = Kv >> 6;  // = 16
    agen_ld(0);
    stageAB(0, 0);
    if (nk > 1) stageAB(1, 64);
    agen_st(0);        // waits s2 loads (oldest) -> B tiles stay in flight
    fence13();         // B0 landed; B1 in flight
    for (int ki = 0; ki < nk; ki++) {
      if (ki + 1 < nk) agen_ld((ki + 1) << 6);
      if (ki + 2 < nk) stageAB((ki + 2) % 3, (ki + 2) << 6);
      if (ki + 1 < nk) agen_st((ki + 1) & 1);  // implicit s2-wait retires B(ki+1)
      compute_tile(ki & 1, ki % 3);
      fence13();
    }
  } else {
    for (int k0 = 0; k0 < Kv; k0 += 64) {
      stageAB(0, k0);
      __syncthreads();
      compute_tile(0, 0);
      __syncthreads();
    }
  }

  if constexpr (MODE == 3) {
    if (job4) {
      // full unscaled Abig: [l1u | L1L1u; l2u+b2 | L2L2u]; /Zgl done by adiv
      u16* abig = (u16*)Cf;
#pragma unroll
      for (int i = 0; i < MI; i++) {
#pragma unroll
        for (int j = 0; j < NJ; j++) {
#pragma unroll
          for (int rg = 0; rg < 4; rg++) {
            int r = r0 + wr * RM + i * 16 + q * 4 + rg;   // 0..255 (stack4 rows)
            int ncol = n0 + wc * RN + j * 16 + mlow;
            int blk = r >> 6, oo = r & 63;
            int drow = ((blk & 1) << 6) + oo;
            float v = acc[i][j][rg];
            if (blk < 2) v += aux3[drow];                 // rb2ext bias fold
            abig[(long long)z * (128 * 2048LL) + (long long)drow * 2048 +
                 (long long)(blk >> 1) * 1024 + ncol] = f2bf(v);
          }
        }
      }
    } else {
      const float* sqb = aux1 + (long long)z * NI;
#pragma unroll
      for (int i = 0; i < MI; i++) {
#pragma unroll
        for (int rg = 0; rg < 4; rg++) {
          int r = r0 + wr * RM + i * 16 + q * 4 + rg;
          float sqi = sqb[r];
          float rsum = 0.f;
#pragma unroll
          for (int j = 0; j < NJ; j++) {
            int ncol = n0 + wc * RN + j * 16 + mlow;
            float d2 = fmaxf(sqi + sqb[ncol] - 2.f * acc[i][j][rg], 0.f);
            float w = __expf(__expf(-d2 * (1.f / 128.f)) + (r == ncol ? 1.f : 0.f) - 2.f);
            Cb[(long long)z * bsC + (long long)r * ldc + ncol] = f2bf(w);
            rsum += w;
          }
          rsum += __shfl_xor(rsum, 1);
          rsum += __shfl_xor(rsum, 2);
          rsum += __shfl_xor(rsum, 4);
          rsum += __shfl_xor(rsum, 8);
          if (mlow == 0) atomicAdd(&Zout[(long long)z * NI + r], rsum);
        }
      }
    }
  } else if constexpr (MODE == 14) {
    // hT write + rank-1 bias (wcs=aux3 x emb2_b=aux1) + column dots w/ atta (aux2)
    float ps1 = 0.f, ps2 = 0.f;
#pragma unroll
    for (int i = 0; i < MI; i++) {
#pragma unroll
      for (int rg = 0; rg < 4; rg++) {
        int r = wr * RM + i * 16 + q * 4 + rg;  // r0 == 0
        int ncol = n0 + wc * RN + mlow;
        float v = acc[i][0][rg] + aux3[r] * aux1[ncol];
        Cb[(long long)z * bsC + (long long)r * ldc + ncol] = f2bf(v);
        ps1 = fmaf(v, aux2[r], ps1);
        ps2 = fmaf(v, aux2[64 + r], ps2);
      }
    }
    ps1 += __shfl_xor(ps1, 16); ps1 += __shfl_xor(ps1, 32);
    ps2 += __shfl_xor(ps2, 16); ps2 += __shfl_xor(ps2, 32);
    float* sred = (float*)As;  // s1: [32 cols][2 wr]; s2 at +64
    const int col = wc * RN + mlow;
    if (q == 0) { sred[col * 2 + wr] = ps1; sred[64 + col * 2 + wr] = ps2; }
    __syncthreads();
    if (tid < 32) {
      float v1 = sred[tid * 2] + sred[tid * 2 + 1];
      float v2 = sred[64 + tid * 2] + sred[64 + tid * 2 + 1];
      Cf[(long long)z * NI + n0 + tid] = v1;
      Zout[(long long)z * NI + n0 + tid] = v2;
      float mx = v2;
      for (int off = 1; off < 32; off <<= 1) mx = fmaxf(mx, __shfl_xor(mx, off));
      if (tid == 0) atomicMax((unsigned*)B2g + z, fkey(mx));
    }
  } else if constexpr (MODE == 13) {
    // ---- stage-1 finish: in-block softmax denominator (BM=32) ----
    float* zred = (float*)xa;            // [32][8]
    float* zinv = (float*)xa + 256;      // [32]
    zred[(tid >> 3) * 8 + (tid & 7)] = zp0;
    __syncthreads();
    if (tid < 32) {
      float sum = 0.f;
#pragma unroll
      for (int j = 0; j < 8; j++) sum += zred[tid * 8 + j];
      zinv[tid] = 1.f / sum;
    }
    __syncthreads();
    float zr[4];
#pragma unroll
    for (int rg = 0; rg < 4; rg++) zr[rg] = zinv[wr * 16 + q * 4 + rg];
    __syncthreads();  // all zinv reads done before xa overwrite
    // ---- x_att tile (relu, scaled) -> xa as A-fragments; uaiw -> Bs ----
#pragma unroll
    for (int j = 0; j < NJ; j++) {
#pragma unroll
      for (int rg = 0; rg < 4; rg++) {
        int row = wr * 16 + q * 4 + rg;
        int col = wc * RN + j * 16 + mlow;
        float v = fmaxf(acc[0][j][rg] * zr[rg], 0.f);
        xa[row * 72 + col] = f2bf(v);
      }
    }
#pragma unroll
    for (int s = 0; s < 2; s++) {
      int cid = tid + s * 256;
      int r = cid >> 3, cc = cid & 7;
      gload16(B2g + r * 64 + ((cc ^ (r & 7)) << 3),
              Bs + ((wbase + s * 256) << 3));
    }
    __syncthreads();
    // ---- stage-2: x_uai tile = xa @ uaiw^T (K=64) ----
    floatx4 acc2[2] = {};
#pragma unroll
    for (int kh = 0; kh < 2; kh++) {
      const int kc = kh * 4 + q;
      short8 a2 = *(const short8*)&xa[(wr * 16 + mlow) * 72 + kc * 8];
#pragma unroll
      for (int j = 0; j < 2; j++) {
        int orow = wc * 32 + j * 16 + mlow;
        short8 b2 = *(const short8*)&Bs[(orow * 8 + (kc ^ (orow & 7))) * 8];
        acc2[j] = __builtin_amdgcn_mfma_f32_16x16x32_bf16(a2, b2, acc2[j], 0, 0, 0);
      }
    }
#pragma unroll
    for (int rg = 0; rg < 4; rg++) {
      int row = r0 + wr * 16 + q * 4 + rg;
      float sqp = 0.f;
#pragma unroll
      for (int j = 0; j < 2; j++) {
        int o = wc * 32 + j * 16 + mlow;
        float v = acc2[j][rg] + aux1[o];
        Cb[(long long)z * bsC + (long long)row * ldc + o] = f2bf(v);
        sqp = fmaf(v, v, sqp);
      }
      sqp += __shfl_xor(sqp, 1);
      sqp += __shfl_xor(sqp, 2);
      sqp += __shfl_xor(sqp, 4);
      sqp += __shfl_xor(sqp, 8);
      if (mlow == 0) atomicAdd(&Zout[(long long)z * NI + row], sqp);
    }
  } else if constexpr (MODE == 5) {
    // rank-1: rb2ext (aux3) x cs2 (aux1) + rl2ext (aux4) x v2 (aux2); bf16 out;
    // LN stats from fp32 values. BM=128 spans both halves: half == wr
    // (waves 0,1 = rows 0..63 = xn; waves 2,3 = rows 64..127 = ft).
    float ts = 0.f, tss = 0.f;
#pragma unroll
    for (int i = 0; i < MI; i++) {
#pragma unroll
      for (int j = 0; j < NJ; j++) {
#pragma unroll
        for (int rg = 0; rg < 4; rg++) {
          int r = wr * RM + i * 16 + q * 4 + rg;   // r0 == 0
          int ncol = n0 + wc * RN + j * 16 + mlow;
          float v = acc[i][j][rg];
          v += aux3[r] * aux1[ncol] + aux4[r] * aux2[ncol];
          Cb[(long long)z * bsC + (long long)r * ldc + ncol] = f2bf(v);
          ts += v;
          tss = fmaf(v, v, tss);
        }
      }
    }
    // per-half block stats: tid 0..127 (wr=0) -> half0; 128..255 -> half1
    float* red = (float*)As;  // 512 floats
    red[tid] = ts; red[256 + tid] = tss;
    __syncthreads();
    for (int st = 64; st > 0; st >>= 1) {
      if ((tid & 127) < st) {
        red[tid] += red[tid + st];
        red[256 + tid] += red[256 + tid + st];
      }
      __syncthreads();
    }
    if (tid == 0) {
      atomicAdd(&Zout[z * 2 + 0], red[0]);
      atomicAdd(&Zout[32 + z * 2 + 0], red[256]);
    }
    if (tid == 128) {
      atomicAdd(&Zout[z * 2 + 1], red[128]);
      atomicAdd(&Zout[32 + z * 2 + 1], red[256 + 128]);
    }
  } else {
    // MODE 15 (GEMM jobs) element-wise epilogue
#pragma unroll
    for (int i = 0; i < MI; i++) {
#pragma unroll
      for (int j = 0; j < NJ; j++) {
#pragma unroll
        for (int rg = 0; rg < 4; rg++) {
          int r = r0 + wr * RM + i * 16 + q * 4 + rg;
          int ncol = n0 + wc * RN + j * 16 + mlow;
          Cb[cboff + (long long)r * ldc + ncol] = f2bf(acc[i][j][rg]);
        }
      }
    }
  }
}

// ---- adiv: Abig W-half /= Zgl (K-indexed) in place. 2M elements ----
__global__ __launch_bounds__(256) void adiv(u16* __restrict__ abig,
                                            const float* __restrict__ Zgl)
{
  const int bid = blockIdx.x;            // 1024: z = bid>>6, row-pair = (bid&63)*2
  const int z = bid >> 6;
  const int r = (bid & 63) * 2;
  const int t = threadIdx.x;
  const int c = t * 4;
  const float4 zv = *(const float4*)(Zgl + (long long)z * NI + c);
  const float i0 = __builtin_amdgcn_rcpf(zv.x);
  const float i1 = __builtin_amdgcn_rcpf(zv.y);
  const float i2 = __builtin_amdgcn_rcpf(zv.z);
  const float i3 = __builtin_amdgcn_rcpf(zv.w);
  u16* base = abig + (long long)z * (128 * 2048LL) + (long long)r * 2048 + c;
#pragma unroll
  for (int rr = 0; rr < 2; rr++) {
    u16* p = base + (long long)rr * 2048;
    uint2 v = *(uint2*)p;
    u16 o[4];
    o[0] = f2bf(bf2f((u16)(v.x & 0xffff)) * i0);
    o[1] = f2bf(bf2f((u16)(v.x >> 16)) * i1);
    o[2] = f2bf(bf2f((u16)(v.y & 0xffff)) * i2);
    o[3] = f2bf(bf2f((u16)(v.y >> 16)) * i3);
    *(uint2*)p = *(uint2*)o;
  }
}

// ---- lap_rowsum + zero-init: blocks <2048 do dr[k][i]; rest zero the atomic region ----
__global__ __launch_bounds__(256) void lap_rowsum(const float* __restrict__ gd,
                                                  float* __restrict__ dr,
                                                  float* __restrict__ zero)
{
  if (blockIdx.x >= 2048) {
    int i = (blockIdx.x - 2048) * 256 + threadIdx.x;
    if (i < ZERON) zero[i] = 0.f;
    return;
  }
  const int ki = blockIdx.x;
  const float* row = gd + (long long)ki * NI;
  float s = 0.f;
  for (int j = threadIdx.x; j < NI; j += 256) s += row[j];
  __shared__ float red[256];
  red[threadIdx.x] = s; __syncthreads();
  for (int st = 128; st > 0; st >>= 1) {
    if (threadIdx.x < st) red[threadIdx.x] += red[threadIdx.x + st];
    __syncthreads();
  }
  if (threadIdx.x == 0) dr[ki] = rsqrtf(red[0] + 1.f);
}

// ---------------- mega_prep: blockIdx-range dispatch of all prep work ----------------
// [0,98)       small weights | [98,1122) emb2_w cast (float4) |
// [1122,1378)  convT | [1378,2402) g2t (float4) | [2402,3426) g1 | [3426,4450) cs1
__global__ __launch_bounds__(256) void mega_prep(
    const float* __restrict__ l1w, const float* __restrict__ l2w,
    const float* __restrict__ l2b, const float* __restrict__ uaiw,
    const float* __restrict__ attW,
    u16* __restrict__ stack4, float* __restrict__ rb2ext, float* __restrict__ rl2ext,
    u16* __restrict__ uaiw_bf, u16* __restrict__ attwT_bf, float* __restrict__ wcs,
    const float* __restrict__ emb2w, u16* __restrict__ emb2w_bf,
    const float* __restrict__ x, const float* __restrict__ ew,
    const float* __restrict__ eb, u16* __restrict__ h0aT,
    const float* __restrict__ gd, const float* __restrict__ dsum,
    u16* __restrict__ g2t, u16* __restrict__ g1,
    float* __restrict__ cs1)
{
  __shared__ float sm[1092];
  const int bid = blockIdx.x;
  const int t = threadIdx.x;
  if (bid < 98) {
    const int gid = bid * 256 + t;
    if (gid < 4096) {
      stack4[gid] = f2bf(l1w[gid]);
    } else if (gid < 8192) {
      stack4[gid] = f2bf(l2w[gid - 4096]);
    } else if (gid < 12288) {
      int tt = gid - 8192, o = tt >> 6, m = tt & 63;
      float s = 0.f;
      for (int c = 0; c < 64; c++) s = fmaf(l1w[o * 64 + c], l1w[c * 64 + m], s);
      stack4[gid] = f2bf(s);
    } else if (gid < 16384) {
      int tt = gid - 12288, o = tt >> 6, m = tt & 63;
      float s = 0.f;
      for (int c = 0; c < 64; c++) s = fmaf(l2w[o * 64 + c], l2w[c * 64 + m], s);
      stack4[gid] = f2bf(s);
    } else if (gid < 16512) {
      int r = gid - 16384;
      rb2ext[r] = (r < 64) ? 0.f : l2b[r - 64];
    } else if (gid < 16640) {
      int r = gid - 16512;
      float v = 0.f;
      if (r >= 64) { int o = r - 64; for (int c = 0; c < 64; c++) v = fmaf(l2w[o * 64 + c], l2b[c], v); }
      rl2ext[r] = v;
    } else if (gid < 20736) {
      uaiw_bf[gid - 16640] = f2bf(uaiw[gid - 16640]);
    } else if (gid < 24832) {
      int idx = gid - 20736;                 // attwT[c][e] = attW[e][c]
      int c = idx >> 6, e = idx & 63;
      attwT_bf[idx] = f2bf(attW[e * 64 + c]);
    } else if (gid < 24896) {
      int c = gid - 24832;                   // wcs[c] = sum_e attW[e][c]
      float s = 0.f;
      for (int e = 0; e < 64; e++) s += attW[e * 64 + c];
      wcs[c] = s;
    }
  } else if (bid < 1122) {
    const long long i = (long long)(bid - 98) * 1024 + t * 4;
    float4 v = *(const float4*)(emb2w + i);
    u16 o4[4] = {f2bf(v.x), f2bf(v.y), f2bf(v.z), f2bf(v.w)};
    *(uint2*)(emb2w_bf + i) = *(const uint2*)o4;
  } else if (bid < 1378) {
    // convT: h0aT[b][n][e], 64 n per block, 4 threads/n each doing 16 e
    const int sub = bid - 1122;
    const int b = sub >> 4;
    const int nc = (sub & 15) * 64;
    float* we = sm;          // [64][16]
    float* be = sm + 1024;   // [64]
    for (int i = t; i < 1024; i += 256) we[i] = ew[i];
    if (t < 64) be[t] = eb[t];
    __syncthreads();
    const int n = nc + (t >> 2);
    const int e0 = (t & 3) * 16;
    const float* xb = x + (long long)b * CI * NI + n;
    float xv[16];
#pragma unroll
    for (int c = 0; c < CI; c++) xv[c] = xb[(long long)c * NI];
    u16 out16[16];
#pragma unroll
    for (int ee = 0; ee < 16; ee++) {
      const int e = e0 + ee;
      float a = be[e];
#pragma unroll
      for (int c = 0; c < CI; c++) a = fmaf(xv[c], we[e * 16 + c], a);
      out16[ee] = f2bf(lrelu01(a));
    }
    u16* dst = h0aT + (long long)b * S1 + (long long)n * 64 + e0;
    *(uint4*)dst = *(uint4*)out16;
    *(uint4*)(dst + 8) = *(uint4*)(out16 + 8);
  } else if (bid < 2402) {
    const int m = bid - 1378;
    const int j = t * 4;
    const float* d = dsum + NI;
    float4 g = *(const float4*)(gd + NN2 + (long long)m * NI + j);
    float dm = d[m];
    float4 dj = *(const float4*)(d + j);
    u16 o4[4];
    o4[0] = f2bf((g.x + (m == j     ? 1.f : 0.f)) * dm * dj.x);
    o4[1] = f2bf((g.y + (m == j + 1 ? 1.f : 0.f)) * dm * dj.y);
    o4[2] = f2bf((g.z + (m == j + 2 ? 1.f : 0.f)) * dm * dj.z);
    o4[3] = f2bf((g.w + (m == j + 3 ? 1.f : 0.f)) * dm * dj.w);
    *(uint2*)(g2t + (long long)m * NI + j) = *(const uint2*)o4;
  } else if (bid < 3426) {
    const int sub = bid - 2402;
    const int bx = (sub & 31) * 32, by = (sub >> 5) * 32;
    const int lx = t & 31, ly = t >> 5;  // 32x8
    float* tile = sm;                    // 32x33
    for (int yy = ly; yy < 32; yy += 8)
      tile[yy * 33 + lx] = gd[(long long)(by + yy) * NI + bx + lx];
    __syncthreads();
    for (int yy = ly; yy < 32; yy += 8) {
      const int i = bx + yy, j = by + lx;
      float v = (tile[lx * 33 + yy] + (i == j ? 1.f : 0.f)) * dsum[i] * dsum[j];
      g1[(long long)i * NI + j] = f2bf(v);
    }
  } else {
    const int n = bid - 3426;
    float s = 0.f;
    for (int i = t; i < NI; i += 256) s = fmaf(gd[(long long)n * NI + i], dsum[i], s);
    float* red = sm;
    red[t] = s; __syncthreads();
    for (int st = 128; st > 0; st >>= 1) {
      if (t < st) red[t] += red[t + st];
      __syncthreads();
    }
    if (t == 0) cs1[n] = dsum[n] * (red[0] + dsum[n]);
  }
}

// ---- LayerNorm apply + GELU + final gating; 512 threads (8 waves) for TLP ----
__global__ __launch_bounds__(512) void ln_final_t(const u16* __restrict__ T,
                                                  const float* __restrict__ stats,
                                                  const float* __restrict__ lnw,
                                                  const float* __restrict__ lnb,
                                                  const float* __restrict__ ct,
                                                  const u16* __restrict__ xuT,
                                                  float* __restrict__ outp)
{
  __shared__ float xs[64 * 65];
  const int blk = blockIdx.x;
  const int b = blk >> 4;
  const int n0 = (blk & 15) << 6;
  const int t = threadIdx.x;
  const int tc = t & 63, tr = t >> 6;  // tr in [0,8)
#pragma unroll
  for (int i = 0; i < 8; i++) {
    int nn = i * 8 + tr;
    xs[tc * 65 + nn] = bf2f(xuT[((long long)b << 16) + (long long)(n0 + nn) * 64 + tc]);
  }
  __syncthreads();
  const float inv_n = 1.f / 65536.f;
  const float m0 = stats[b * 2] * inv_n;
  const float m1 = stats[b * 2 + 1] * inv_n;
  const float rs0 = rsqrtf(fmaxf(stats[32 + b * 2] * inv_n - m0 * m0, 0.f) + 1e-5f);
  const float rs1 = rsqrtf(fmaxf(stats[32 + b * 2 + 1] * inv_n - m1 * m1, 0.f) + 1e-5f);
#pragma unroll
  for (int j = 0; j < 8; j++) {
    const int c = j * 8 + tr;
    const int n = n0 + tc;
    const int rem = c * NI + n;
    const long long toff = (long long)b * S2 + rem;
    const float t0 = bf2f(T[toff]);
    const float t1 = bf2f(T[toff + S1]);
    const float w = lnw[rem], bb = lnb[rem];
    const float xn = (t0 - m0) * rs0 * w + bb;
    float ft = (t1 - m1) * rs1 * w + bb;
    ft = 0.5f * ft * (1.f + erff(ft * 0.70710678118654752f));
    const float u = xs[c * 65 + tc];
    const long long oidx = ((long long)b << 16) + rem;
    const float cn = fmaf(ft, ct[oidx] - xn, xn);
    const float el = cn > 0.f ? cn : expm1f(cn);
    outp[oidx] = fmaf(ft, el - u, u);
    outp[BCN + oidx] = cn;
  }
}

extern "C" void kernel_launch(void* const* d_in, const int* in_sizes, int n_in,
                              void* d_out, int out_size, void* d_ws, size_t ws_size,
                              hipStream_t stream)
{
  (void)in_sizes; (void)n_in; (void)out_size; (void)ws_size;
  const float* x      = (const float*)d_in[0];
  const float* ct     = (const float*)d_in[1];
  const float* gdata  = (const float*)d_in[2];
  const float* emb_w  = (const float*)d_in[3];
  const float* emb_b  = (const float*)d_in[4];
  const float* emb2_w = (const float*)d_in[5];
  const float* emb2_b = (const float*)d_in[6];
  const float* att_W  = (const float*)d_in[7];
  const float* att_a  = (const float*)d_in[8];
  // d_in[9] att_GL unused: softmax(relu(GL GL^T)) > 0 everywhere -> mask is a no-op
  const float* uai_w  = (const float*)d_in[10];
  const float* uai_b  = (const float*)d_in[11];
  const float* lin1_w = (const float*)d_in[12];
  const float* lin2_w = (const float*)d_in[13];
  const float* lin2_b = (const float*)d_in[14];
  const float* ln_w   = (const float*)d_in[15];
  const float* ln_b   = (const float*)d_in[16];
  float* outp = (float*)d_out;

  float* ws = (float*)d_ws;
  long long o = 0;
  auto af = [&](long long n) { float* p = ws + o; o += (n + 63) & ~63LL; return p; };
  auto au = [&](long long n) { return (u16*)af((n + 1) / 2); };

  float* s1      = af(BNv);
  float* s2      = af(BNv);
  float* dsum    = af(2 * NI);
  float* cs1v    = af(NI);
  float* cs2v    = af(NI);
  float* v2v     = af(NI);
  float* rb2ext  = af(128);
  float* rl2ext  = af(128);
  float* wcs     = af(64);
  // contiguous zero-init region: Zgl, sqv, stats(64), s2mU(16)
  float* zeroreg = af(ZERON);
  float* Zgl     = zeroreg;
  float* sqv     = zeroreg + BNv;
  float* stats   = zeroreg + 2 * BNv;
  unsigned* s2mU = (unsigned*)(stats + 64);
  u16* Tacc      = au(S2 * BATCH);   // bf16
  u16* emb2w_bf  = au(NN2);
  u16* h0aTb     = au(S1 * BATCH);   // [b][n][e]
  u16* ybf       = au(S1 * BATCH);   // y = attW^T @ h0a, [b][c][n]
  u16* hTb       = au(S1 * BATCH);   // [b][c][n]
  u16* xuaiTb    = au(S1 * BATCH);   // [b][n][c]
  u16* g1b       = au(NN2);
  u16* g2tb      = au(NN2);
  u16* G12b      = au(NN2);
  u16* Abig      = au((long long)BATCH * 128 * 2048);
  u16* stack4    = au(256 * 64);
  u16* uaiw_bf   = au(CE * CE);
  u16* attwT_bf  = au(CE * CE);
  u16* bigW      = au(BNN);  // 32 MB: gram W (att-p computed on the fly)

  // lap_rowsum also zero-inits the atomic region (no separate memset node)
  lap_rowsum<<<2048 + (ZERON + 255) / 256, 256, 0, stream>>>(gdata, dsum, zeroreg);

  mega_prep<<<4450, 256, 0, stream>>>(
      lin1_w, lin2_w, lin2_b, uai_w, att_W,
      stack4, rb2ext, rl2ext, uaiw_bf, attwT_bf, wcs,
      emb2_w, emb2w_bf, x, emb_w, emb_b, h0aTb,
      gdata, dsum, g2tb, g1b, cs1v);

  // merged dispatch: [0,512) G12t=(g1@g2)^T | [512,1536) csv2 rows |
  // [1536,2048) y = attW^T @ h0a (independent chains joined to fill the machine)
  mgemm<32, 64, 15><<<2048, 256, 0, stream>>>(
      g2tb, g1b, attwT_bf, NI, NI, NI, NI, 0, (long long)(ybf - G12b),
      cs2v, G12b, NI, 0, cs1v, dsum + NI, gdata + NN2, (const float*)h0aTb, v2v);

  // hT[b][c][n'] = y @ emb2w^T + wcs (x) emb2_b; epilogue computes s1/s2/s2max
  mgemm<64, 32, 14><<<512, 256, 0, stream>>>(
      ybf, emb2w_bf, (const u16*)s2mU, NI, NI, NI, NI, S1, 0,
      s1, hTb, NI, S1, emb2_b, att_a, wcs, nullptr, s2);

  // fused two-stage: x_att = relu((p@h)/Z) then x_uai = x_att @ uaiw^T + uai_b
  mgemm<32, 64, 13><<<512, 256, 0, stream>>>(
      hTb, hTb, uaiw_bf, NI, NI, NI, NI, 0, S1,
      nullptr, xuaiTb, CE, S1, uai_b, s1, s2, (const float*)s2mU, sqv);

  // gram/gl weights (4096 XCD-grouped blocks) + FULL unscaled Abig (1024 blocks)
  mgemm<64, 64, 3><<<5120, 256, 0, stream>>>(
      xuaiTb, xuaiTb, nullptr, CE, CE, CE, CE, S1, S1,
      (float*)Abig, bigW, NI, NN2, sqv, (const float*)stack4, rb2ext, nullptr, Zgl);

  // Abig W-half /= Zgl (one-shot; keeps mode 5's hot loop pure)
  adiv<<<1024, 256, 0, stream>>>(Abig, Zgl);

  // Tacc(bf16) = Abig @ [W ; G12t] + b2 (x) cs2 + (L2 b2) (x) v2, + LN stats;
  // BM=128xBN=64 m97-shape tile (16 MFMA/K-step/wave), 256 blocks, L2-warm bigW
  mgemm<128, 64, 5><<<256, 256, 0, stream>>>(
      Abig, bigW, G12b, NI, 2 * NI, 2048, NI, (long long)128 * 2048, NN2,
      nullptr, Tacc, NI, S2, cs2v, v2v, rb2ext, rl2ext, stats);

  ln_final_t<<<256, 512, 0, stream>>>(Tacc, stats, ln_w, ln_b, ct, xuaiTb, outp);
}